// Round 8
// baseline (39.136 us; speedup 1.0000x reference)
//
#include <hip/hip_runtime.h>

// Lattice geometry (fixed by the reference problem)
constexpr int TD = 32, XD = 16, YD = 16, ZD = 16;
constexpr int NSITE  = TD * XD * YD * ZD;   // 131072
constexpr int PLANE  = NSITE * 3;           // 393216 float4s per batch plane
constexpr int NBATCH = 16;
constexpr int WPB    = 4;                   // waves per block (256 threads)

typedef float v4f __attribute__((ext_vector_type(4)));

__global__ __launch_bounds__(256) void qshift_kernel(
    const float* __restrict__ field,   // [B, site, 3, 4] = [B][PLANE] float4
    const float* __restrict__ gauge,   // [4, site, 3, 3]
    const int*   __restrict__ dir_p,
    float*       __restrict__ out)     // [B][PLANE] float4
{
    // wave-local staging: 64 own + 2 low-halo + 2 high-halo float4s
    __shared__ v4f stage[WPB][68];

    const int lane = threadIdx.x & 63;
    const int w    = threadIdx.x >> 6;
    const int jj   = blockIdx.x * 256 + threadIdx.x;   // [0, PLANE)
    const int b    = blockIdx.y;                        // batch plane
    const int dir  = *dir_p;                            // wave-uniform

    const v4f* f4 = (const v4f*)field;
    v4f*       o4 = (v4f*)out;
    const long pb = (long)b * PLANE;

    if (dir == 0) {  // identity copy, dense
        __builtin_nontemporal_store(f4[pb + jj], &o4[pb + jj]);
        return;
    }

    const int d     = (dir > 0) ? dir : -dir;          // 1..4
    const int a     = d - 1;                           // lattice axis
    const int shift = (a == 0) ? 12 : (a == 1) ? 8 : (a == 2) ? 4 : 0;
    const int len   = (a == 0) ? TD : 16;

    // source float4 index within a batch plane, for output float4 index j
    auto srcidx = [&](int j) -> int {
        const int s  = (int)((unsigned)j / 3u);
        const int cc = j - s * 3;
        const int cb = (s >> shift) & (len - 1);
        const int cn = (dir > 0) ? ((cb == 0) ? (len - 1) : (cb - 1))
                                 : ((cb == len - 1) ? 0 : (cb + 1));
        return (s + ((cn - cb) << shift)) * 3 + cc;
    };

    const int site = (int)((unsigned)jj / 3u);
    const int c    = jj - site * 3;
    const int ca   = (site >> shift) & (len - 1);
    const int cs   = (dir > 0) ? ((ca == 0) ? (len - 1) : (ca - 1))
                               : ((ca == len - 1) ? 0 : (ca + 1));
    const int ssite   = site + ((cs - ca) << shift);
    const int src_own = ssite * 3 + c;

    // gauge row for output color c
    const int gsite = (dir > 0) ? ssite : site;        // dagger(roll) vs plain
    const float* gp = gauge + ((long)a * NSITE + (long)gsite) * 9;
    float m0, m1, m2;
    if (dir > 0) { m0 = gp[c];     m1 = gp[3 + c];     m2 = gp[6 + c];     } // g^T row
    else         { m0 = gp[3 * c]; m1 = gp[3 * c + 1]; m2 = gp[3 * c + 2]; }

    // stage own float4
    stage[w][2 + lane] = f4[pb + src_own];

    // halo: lanes 0,1 -> slots 0,1 (j = wbase-2, wbase-1);
    //       lanes 2,3 -> slots 66,67 (j = wbase+64, wbase+65)
    if (lane < 4) {
        const int joff = (lane < 2) ? (lane - 2) : (62 + lane);  // -2,-1,64,65
        int jh = (jj - lane) + joff;
        jh = (jh < 0) ? 0 : ((jh >= PLANE) ? (PLANE - 1) : jh);  // clamp (unused slots)
        const int slot = (lane < 2) ? lane : (lane + 64);        // 0,1,66,67
        stage[w][slot] = f4[pb + srcidx(jh)];
    }

    // consume: lane's site occupies stage slots p..p+2 (p = lane + 2 - c)
    const int p = lane + 2 - c;
    const v4f f0 = stage[w][p];
    const v4f f1 = stage[w][p + 1];
    const v4f f2 = stage[w][p + 2];
    const v4f o  = m0 * f0 + m1 * f1 + m2 * f2;
    __builtin_nontemporal_store(o, &o4[pb + jj]);
}

extern "C" void kernel_launch(void* const* d_in, const int* in_sizes, int n_in,
                              void* d_out, int out_size, void* d_ws, size_t ws_size,
                              hipStream_t stream) {
    const float* field = (const float*)d_in[0];
    const float* gauge = (const float*)d_in[1];
    const int*   dirp  = (const int*)d_in[2];
    float*       outp  = (float*)d_out;

    dim3 grid(PLANE / 256, NBATCH);   // (1536, 16), x-fastest => contiguous sweep
    qshift_kernel<<<grid, 256, 0, stream>>>(field, gauge, dirp, outp);
}

// Round 9
// 37.171 us; speedup vs baseline: 1.0529x; 1.0529x over previous
//
#include <hip/hip_runtime.h>

// Lattice geometry (fixed by the reference problem)
constexpr int TD = 32, XD = 16, YD = 16, ZD = 16;
constexpr int NSITE  = TD * XD * YD * ZD;   // 131072
constexpr int PLANE  = NSITE * 3;           // 393216 float4s per batch plane
constexpr int NBATCH = 16;
constexpr int BPT    = 8;                   // batches per thread
constexpr int NGROUP = NBATCH / BPT;        // 2
constexpr int WPB    = 4;                   // waves per block (256 threads)

typedef float v4f __attribute__((ext_vector_type(4)));

__global__ __launch_bounds__(256) void qshift_kernel(
    const float* __restrict__ field,   // [B, site, 3, 4] = [B][PLANE] float4
    const float* __restrict__ gauge,   // [4, site, 3, 3]
    const int*   __restrict__ dir_p,
    float*       __restrict__ out)     // [B][PLANE] float4
{
    // wave-local staging: 64 own + 2 low-halo + 2 high-halo float4s, per batch
    __shared__ v4f stage[WPB][BPT][68];

    const int lane = threadIdx.x & 63;
    const int w    = threadIdx.x >> 6;
    const int jj   = blockIdx.x * 256 + threadIdx.x;   // [0, PLANE)
    const int b0   = blockIdx.y * BPT;
    const int dir  = *dir_p;                            // wave-uniform

    const v4f* f4 = (const v4f*)field;
    v4f*       o4 = (v4f*)out;

    if (dir == 0) {  // identity copy, dense
        #pragma unroll
        for (int k = 0; k < BPT; ++k) {
            const long idx = (long)(b0 + k) * PLANE + jj;
            __builtin_nontemporal_store(f4[idx], &o4[idx]);
        }
        return;
    }

    const int d     = (dir > 0) ? dir : -dir;          // 1..4
    const int a     = d - 1;                           // lattice axis
    const int shift = (a == 0) ? 12 : (a == 1) ? 8 : (a == 2) ? 4 : 0;
    const int len   = (a == 0) ? TD : 16;

    // source float4 index within a batch plane, for output float4 index j
    auto srcidx = [&](int j) -> int {
        const int s  = (int)((unsigned)j / 3u);
        const int cc = j - s * 3;
        const int cb = (s >> shift) & (len - 1);
        const int cn = (dir > 0) ? ((cb == 0) ? (len - 1) : (cb - 1))
                                 : ((cb == len - 1) ? 0 : (cb + 1));
        return (s + ((cn - cb) << shift)) * 3 + cc;
    };

    const int site = (int)((unsigned)jj / 3u);
    const int c    = jj - site * 3;
    const int ca   = (site >> shift) & (len - 1);
    const int cs   = (dir > 0) ? ((ca == 0) ? (len - 1) : (ca - 1))
                               : ((ca == len - 1) ? 0 : (ca + 1));
    const int ssite   = site + ((cs - ca) << shift);
    const int src_own = ssite * 3 + c;

    // gauge row for output color c (load once, reuse across BPT batches)
    const int gsite = (dir > 0) ? ssite : site;        // dagger(roll) vs plain
    const float* gp = gauge + ((long)a * NSITE + (long)gsite) * 9;
    float m0, m1, m2;
    if (dir > 0) { m0 = gp[c];     m1 = gp[3 + c];     m2 = gp[6 + c];     } // g^T row
    else         { m0 = gp[3 * c]; m1 = gp[3 * c + 1]; m2 = gp[3 * c + 2]; }

    // halo: lanes 0,1 -> slots 0,1 (j = wbase-2, wbase-1);
    //       lanes 2,3 -> slots 66,67 (j = wbase+64, wbase+65)
    int halo_slot = 0, src_halo = 0;
    if (lane < 4) {
        const int joff = (lane < 2) ? (lane - 2) : (62 + lane);  // -2,-1,64,65
        int jh = (jj - lane) + joff;
        jh = (jh < 0) ? 0 : ((jh >= PLANE) ? (PLANE - 1) : jh);  // clamp (unused slots)
        halo_slot = (lane < 2) ? lane : (lane + 64);             // 0,1,66,67
        src_halo  = srcidx(jh);
    }

    // --- explicit register staging: issue ALL global loads first (8-deep MLP)
    v4f rown[BPT];
    #pragma unroll
    for (int k = 0; k < BPT; ++k)
        rown[k] = f4[(long)(b0 + k) * PLANE + src_own];

    v4f rh0, rh1, rh2, rh3, rh4, rh5, rh6, rh7;
    if (lane < 4) {
        rh0 = f4[(long)(b0 + 0) * PLANE + src_halo];
        rh1 = f4[(long)(b0 + 1) * PLANE + src_halo];
        rh2 = f4[(long)(b0 + 2) * PLANE + src_halo];
        rh3 = f4[(long)(b0 + 3) * PLANE + src_halo];
        rh4 = f4[(long)(b0 + 4) * PLANE + src_halo];
        rh5 = f4[(long)(b0 + 5) * PLANE + src_halo];
        rh6 = f4[(long)(b0 + 6) * PLANE + src_halo];
        rh7 = f4[(long)(b0 + 7) * PLANE + src_halo];
    }

    // --- write staged data to LDS
    #pragma unroll
    for (int k = 0; k < BPT; ++k)
        stage[w][k][2 + lane] = rown[k];
    if (lane < 4) {
        stage[w][0][halo_slot] = rh0;
        stage[w][1][halo_slot] = rh1;
        stage[w][2][halo_slot] = rh2;
        stage[w][3][halo_slot] = rh3;
        stage[w][4][halo_slot] = rh4;
        stage[w][5][halo_slot] = rh5;
        stage[w][6][halo_slot] = rh6;
        stage[w][7][halo_slot] = rh7;
    }

    // consume: lane's site occupies stage slots p..p+2 (p = lane + 2 - c)
    const int p = lane + 2 - c;
    #pragma unroll
    for (int k = 0; k < BPT; ++k) {
        const v4f f0 = stage[w][k][p];
        const v4f f1 = stage[w][k][p + 1];
        const v4f f2 = stage[w][k][p + 2];
        const v4f o  = m0 * f0 + m1 * f1 + m2 * f2;
        __builtin_nontemporal_store(o, &o4[(long)(b0 + k) * PLANE + jj]);
    }
}

extern "C" void kernel_launch(void* const* d_in, const int* in_sizes, int n_in,
                              void* d_out, int out_size, void* d_ws, size_t ws_size,
                              hipStream_t stream) {
    const float* field = (const float*)d_in[0];
    const float* gauge = (const float*)d_in[1];
    const int*   dirp  = (const int*)d_in[2];
    float*       outp  = (float*)d_out;

    dim3 grid(PLANE / 256, NGROUP);   // (1536, 2), x-fastest => contiguous sweep
    qshift_kernel<<<grid, 256, 0, stream>>>(field, gauge, dirp, outp);
}